// Round 6
// baseline (700.196 us; speedup 1.0000x reference)
//
#include <hip/hip_runtime.h>
#include <hip/hip_bf16.h>
#include <cstdint>
#include <cstdio>

typedef unsigned short u16;
typedef unsigned int   u32;
typedef __attribute__((ext_vector_type(8))) short bf16x8;   // 8 bf16 (4 VGPRs)
typedef __attribute__((ext_vector_type(4))) float f32x4;
typedef __attribute__((ext_vector_type(4))) u16   u16x4;
typedef __attribute__((ext_vector_type(8))) u16   u16x8;

#define GLOBAL_AS __attribute__((address_space(1)))
#define LDS_AS    __attribute__((address_space(3)))

static __device__ __forceinline__ u16 f2bf(float f) {
  u32 u = __builtin_bit_cast(u32, f);
  u = (u + 0x7fffu + ((u >> 16) & 1u)) >> 16;   // RNE
  return (u16)u;
}
static __device__ __forceinline__ float bf2f(u16 v) {
  return __builtin_bit_cast(float, (u32)v << 16);
}
static __device__ __forceinline__ void gload_lds16(const void* g, void* l) {
  __builtin_amdgcn_global_load_lds((GLOBAL_AS u32*)g, (LDS_AS u32*)l, 16, 0, 0);
}

// ---------------------------------------------------------------------------
__global__ void k_cvt(const float* __restrict__ src, int ld, int c0,
                      int rows_src, int cols4, int total4,
                      u16* __restrict__ dst, int ldd, int dcol) {
  int gid = blockIdx.x * 256 + threadIdx.x;
  if (gid >= total4) return;
  int r = gid / cols4;
  int c = (gid - r * cols4) * 4;
  u16x4 o = {0, 0, 0, 0};
  if (r < rows_src) {
    const float4 v = *(const float4*)&src[(size_t)r * ld + c0 + c];
    o[0] = f2bf(v.x); o[1] = f2bf(v.y); o[2] = f2bf(v.z); o[3] = f2bf(v.w);
  }
  *(u16x4*)&dst[(size_t)r * ldd + dcol + c] = o;
}

// ---------------------------------------------------------------------------
__global__ void k_init(const float* __restrict__ rough,
                       const float* __restrict__ bout,
                       float* __restrict__ out) {
  int i = blockIdx.x * 256 + threadIdx.x;
  if (i >= 1024 * 65) return;
  int bi = i / 65, c = i - bi * 65;
  out[i] = (c == 0) ? 1e-7f : rough[bi * 64 + c - 1] + bout[0];
}

// ---------------------------------------------------------------------------
// gemm128: 128x128 2-phase kernel, used only for the tiny Aproj GEMM.
// bias (b1) folded into the bf16 output.
__global__ __launch_bounds__(256)
void gemm128(const u16* __restrict__ A, int lda,
             const u16* __restrict__ B, int ldb, int Ksteps,
             u16* __restrict__ C, int ldc, const float* __restrict__ bias) {
  __shared__ u16 As[128 * 64];
  __shared__ u16 Bs[128 * 64];
  const int t = threadIdx.x;
  const int w = t >> 6, l = t & 63;
  const int wr = w >> 1, wc = w & 1;
  const int brow = blockIdx.x * 128;
  const int bcol = blockIdx.y * 128;
  const int srow = t >> 3;
  const int scol = (t & 7) * 8;
  const int gsw  = (((t & 7) ^ ((t >> 3) & 7))) * 8;

  f32x4 acc[4][4] = {};
  for (int ks = 0; ks < Ksteps; ++ks) {
    const int kb = ks * 64;
#pragma unroll
    for (int q = 0; q < 4; ++q) {
      int r = q * 32 + srow;
      gload_lds16(A + (size_t)(brow + r) * lda + kb + gsw, &As[r * 64 + scol]);
      gload_lds16(B + (size_t)(bcol + r) * ldb + kb + gsw, &Bs[r * 64 + scol]);
    }
    __syncthreads();
#pragma unroll
    for (int kk = 0; kk < 2; ++kk) {
      bf16x8 af[4], bfr[4];
      const int pg = ((kk * 4 + (l >> 4)) ^ (l & 7)) * 8;
#pragma unroll
      for (int m = 0; m < 4; ++m)
        af[m] = *(const bf16x8*)&As[(wr * 64 + m * 16 + (l & 15)) * 64 + pg];
#pragma unroll
      for (int n = 0; n < 4; ++n)
        bfr[n] = *(const bf16x8*)&Bs[(wc * 64 + n * 16 + (l & 15)) * 64 + pg];
#pragma unroll
      for (int m = 0; m < 4; ++m)
#pragma unroll
        for (int n = 0; n < 4; ++n)
          acc[m][n] = __builtin_amdgcn_mfma_f32_16x16x32_bf16(af[m], bfr[n], acc[m][n], 0, 0, 0);
    }
    __syncthreads();
  }
#pragma unroll
  for (int m = 0; m < 4; ++m)
#pragma unroll
    for (int n = 0; n < 4; ++n)
#pragma unroll
      for (int reg = 0; reg < 4; ++reg) {
        int row = brow + wr * 64 + m * 16 + (l >> 4) * 4 + reg;
        int col = bcol + wc * 64 + n * 16 + (l & 15);
        float v = acc[m][n][reg] + (bias ? bias[col] : 0.f);
        C[(size_t)row * ldc + col] = f2bf(v);
      }
}

// ---------------------------------------------------------------------------
// gemm256: 256x256, BK=64, 512 thr (8 waves 2Mx4N), r5-proven phase shape.
// FUSED=false: plain A via gload_lds, manual vmcnt(6) ledger (unchanged, r5).
// FUSED=true: A built on the fly (Cmat fusion). A[g][k]=bf16(a16[bi][k]*
//   allm16[mi][k]) for k<1024, bf16(pw[g][k-1024]) for tile NT-1.
//   q1: issue gathers (t+1,h0) -> regs; q2: cvt+ds_write h0, issue h1,
//   stageB(t+2,h0); q3: cvt+ds_write h1, stageB(t+2,h1).
//   Compiler-inserted vmcnt for gather uses subsumes B readiness (gathers
//   issued after B stages; their waits drain older B loads). ds_write
//   visibility: pre-barrier lgkmcnt(0) at q2/q3. Writes target regions whose
//   last reader finished >=1 barrier ago (opposite buffer).
// Epilogue (FUSED): Bproj 256-slice staged into LDS (reused As/Bs space) with
//   source-side XOR swizzle key=(row>>1)&7 (kills the 4-way conflict seen r5).
template<bool FUSED>
__global__ __launch_bounds__(512, 1)
void gemm256(const u16* __restrict__ A, int lda,
             const u16* __restrict__ B, int ldb, int NT,
             u16* __restrict__ C, int ldc,
             const u16* __restrict__ a16, const u16* __restrict__ allm16,
             const float* __restrict__ pw,
             const u16* __restrict__ Aproj, const u16* __restrict__ Bproj,
             const float* __restrict__ Wout,
             const int* __restrict__ topidx, float* __restrict__ out) {
  extern __shared__ u16 lds[];
  u16* As = lds;                        // [2buf][2half][128][64], rows bit5-interleaved
  u16* Bs = lds + 2 * 2 * 128 * 64;     // [2buf][256][64]

  const int t = threadIdx.x;
  const int l = t & 63;
  const int w = t >> 6;                 // 0..7
  const int wrow = w >> 2, wcol = w & 3;
  const int brow = blockIdx.x * 256;
  const int bcol = blockIdx.y * 256;

  const int sr  = t >> 3;               // 0..63
  const int sc  = (t & 7) * 8;          // linear LDS dest col
  const int gsw = ((t & 7) ^ (sr & 7)) * 8;  // pre-swizzled global col

  int mi_[2][2], bi_[2][2], grow_[2][2];
  if constexpr (FUSED) {
#pragma unroll
    for (int h = 0; h < 2; ++h)
#pragma unroll
      for (int s = 0; s < 2; ++s) {
        int lr = sr + 64 * s;
        int g  = ((lr >> 5) << 6) + h * 32 + (lr & 31);
        grow_[h][s] = brow + g;
        mi_[h][s]   = topidx[brow + g];
        bi_[h][s]   = (brow + g) >> 6;
      }
  }

  auto stageA = [&](int kt, int h) {    // FUSED=false only
    if (kt >= NT) return;
#pragma unroll
    for (int s = 0; s < 2; ++s) {
      int lr = sr + 64 * s;
      int g  = ((lr >> 5) << 6) + h * 32 + (lr & 31);
      gload_lds16(A + (size_t)(brow + g) * lda + kt * 64 + gsw,
                  &As[(((kt & 1) * 2 + h) * 128 + lr) * 64 + sc]);
    }
  };
  auto stageB = [&](int kt, int h) {
    if (kt >= NT) return;
#pragma unroll
    for (int s = 0; s < 2; ++s) {
      int lr = h * 128 + sr + 64 * s;
      gload_lds16(B + (size_t)(bcol + lr) * ldb + kt * 64 + gsw,
                  &Bs[((kt & 1) * 256 + lr) * 64 + sc]);
    }
  };
  auto issueG = [&](int kt1, int h, u16x8* ga, u16x8* gb, float4 (*gp)[2]) {
    if (kt1 >= NT) return;
#pragma unroll
    for (int s = 0; s < 2; ++s) {
      int lr  = sr + 64 * s;
      int swc = sc ^ ((lr & 7) << 3);
      if (kt1 == NT - 1) {              // pw tile
        const float* p = &pw[(size_t)grow_[h][s] * 64 + swc];
        gp[s][0] = *(const float4*)p;
        gp[s][1] = *(const float4*)(p + 4);
      } else {
        int col = kt1 * 64 + swc;
        ga[s] = *(const u16x8*)&a16[(size_t)bi_[h][s] * 1024 + col];
        gb[s] = *(const u16x8*)&allm16[(size_t)mi_[h][s] * 1024 + col];
      }
    }
  };
  auto writeA = [&](int kt1, int h, u16x8* ga, u16x8* gb, float4 (*gp)[2]) {
    if (kt1 >= NT) return;
#pragma unroll
    for (int s = 0; s < 2; ++s) {
      int lr = sr + 64 * s;
      u16x8 o;
      if (kt1 == NT - 1) {
        o[0] = f2bf(gp[s][0].x); o[1] = f2bf(gp[s][0].y);
        o[2] = f2bf(gp[s][0].z); o[3] = f2bf(gp[s][0].w);
        o[4] = f2bf(gp[s][1].x); o[5] = f2bf(gp[s][1].y);
        o[6] = f2bf(gp[s][1].z); o[7] = f2bf(gp[s][1].w);
      } else {
#pragma unroll
        for (int j = 0; j < 8; ++j) o[j] = f2bf(bf2f(ga[s][j]) * bf2f(gb[s][j]));
      }
      *(u16x8*)&As[(((kt1 & 1) * 2 + h) * 128 + lr) * 64 + sc] = o;
    }
  };

  f32x4 acc[8][4] = {};

  // ---- prologue ----
  if constexpr (FUSED) {
    u16x8 pga0[2], pgb0[2], pga1[2], pgb1[2];
    float4 pgp0[2][2], pgp1[2][2];
    issueG(0, 0, pga0, pgb0, pgp0);
    issueG(0, 1, pga1, pgb1, pgp1);
    stageB(0, 0); stageB(0, 1); stageB(1, 0); stageB(1, 1);
    writeA(0, 0, pga0, pgb0, pgp0);     // compiler waits the gathers
    writeA(0, 1, pga1, pgb1, pgp1);
    asm volatile("s_waitcnt lgkmcnt(0)" ::: "memory");
    asm volatile("s_waitcnt vmcnt(4)" ::: "memory");   // B(0) landed, B(1) in flight
  } else {
    stageB(0, 0); stageB(0, 1); stageA(0, 0); stageA(0, 1);
    stageB(1, 0); stageB(1, 1);
    asm volatile("s_waitcnt vmcnt(6)" ::: "memory");   // B(0)+Ah0(0) landed
  }
  __builtin_amdgcn_s_barrier();

  for (int kt = 0; kt < NT; ++kt) {
    const int cbuf = kt & 1;
    bf16x8 bfr[4][2];                   // B frags, live all 4 phases
    u16x8 ga0[2], gb0[2], ga1[2], gb1[2];
    float4 gp0[2][2], gp1[2][2];
#pragma unroll
    for (int q = 0; q < 4; ++q) {
      // --- ds reads (pre-barrier) ---
      if (q == 0) {
#pragma unroll
        for (int n = 0; n < 4; ++n) {
          int row = wcol * 64 + n * 16 + (l & 15);
#pragma unroll
          for (int kk = 0; kk < 2; ++kk) {
            int gran = (kk * 4 + (l >> 4)) ^ (l & 7);
            bfr[n][kk] = *(const bf16x8*)&Bs[(cbuf * 256 + row) * 64 + gran * 8];
          }
        }
      }
      bf16x8 af[2][2];
#pragma unroll
      for (int m2 = 0; m2 < 2; ++m2) {
        int m = 2 * q + m2;
        int g = wrow * 128 + m * 16 + (l & 15);
        int lra = ((g >> 6) << 5) + (g & 31);
#pragma unroll
        for (int kk = 0; kk < 2; ++kk) {
          int gran = (kk * 4 + (l >> 4)) ^ (l & 7);
          af[m2][kk] = *(const bf16x8*)&As[((cbuf * 2 + (q & 1)) * 128 + lra) * 64 + gran * 8];
        }
      }

      // --- staging work ---
      if constexpr (FUSED) {
        if (q == 1) {
          issueG(kt + 1, 0, ga0, gb0, gp0);
        } else if (q == 2) {
          writeA(kt + 1, 0, ga0, gb0, gp0);       // compiler vmcnt for ga0
          issueG(kt + 1, 1, ga1, gb1, gp1);
          stageB(kt + 2, 0);
          asm volatile("s_waitcnt lgkmcnt(0)" ::: "memory");  // drain ds_writes pre-barrier
        } else if (q == 3) {
          writeA(kt + 1, 1, ga1, gb1, gp1);
          stageB(kt + 2, 1);
          asm volatile("s_waitcnt lgkmcnt(0)" ::: "memory");
        }
      } else {
        if      (q == 0) stageA(kt + 1, 0);
        else if (q == 1) stageA(kt + 1, 1);
        else if (q == 2) stageB(kt + 2, 0);
        else             stageB(kt + 2, 1);
      }

      if (q == 0) asm volatile("s_waitcnt lgkmcnt(8)" ::: "memory");
      __builtin_amdgcn_s_barrier();
      asm volatile("s_waitcnt lgkmcnt(0)" ::: "memory");
      __builtin_amdgcn_sched_barrier(0);
      __builtin_amdgcn_s_setprio(1);
#pragma unroll
      for (int m2 = 0; m2 < 2; ++m2)
#pragma unroll
        for (int n = 0; n < 4; ++n)
#pragma unroll
          for (int kk = 0; kk < 2; ++kk)
            acc[2 * q + m2][n] = __builtin_amdgcn_mfma_f32_16x16x32_bf16(
                af[m2][kk], bfr[n][kk], acc[2 * q + m2][n], 0, 0, 0);
      __builtin_amdgcn_s_setprio(0);

      if constexpr (!FUSED) {           // r5 counted ledger, unchanged
        if (q == 0) {
          if (kt + 1 < NT) asm volatile("s_waitcnt vmcnt(6)" ::: "memory");
          else             asm volatile("s_waitcnt vmcnt(0)" ::: "memory");
        } else if (q == 3 && kt + 1 < NT) {
          if (kt + 2 < NT) asm volatile("s_waitcnt vmcnt(6)" ::: "memory");
          else             asm volatile("s_waitcnt vmcnt(2)" ::: "memory");
        }
      }
      __builtin_amdgcn_s_barrier();
    }
  }

  // --- epilogue ---
  if constexpr (FUSED) {
    __syncthreads();
    u16* Pb = lds;                      // [256][256] reuse, src-swizzled key=(row>>1)&7
#pragma unroll
    for (int pass = 0; pass < 16; ++pass) {
      int rr = pass * 16 + (t >> 5);
      int mi = topidx[brow + rr];
      int cc = (t & 31) * 8;
      int scc = cc ^ (((rr >> 1) & 7) << 3);
      gload_lds16(&Bproj[(size_t)mi * 1024 + bcol + scc], &Pb[rr * 256 + cc]);
    }
    asm volatile("s_waitcnt vmcnt(0)" ::: "memory");
    __syncthreads();

    float wo[4], av[2][4];
    const int bi0 = (brow >> 6) + wrow * 2;
#pragma unroll
    for (int n = 0; n < 4; ++n) {
      int col = bcol + wcol * 64 + n * 16 + (l & 15);
      wo[n] = Wout[col];
#pragma unroll
      for (int j = 0; j < 2; ++j)
        av[j][n] = bf2f(Aproj[(size_t)(bi0 + j) * 1024 + col]);   // b1 pre-folded
    }
#pragma unroll
    for (int m = 0; m < 8; ++m) {
#pragma unroll
      for (int reg = 0; reg < 4; ++reg) {
        int lrow = wrow * 128 + m * 16 + (l >> 4) * 4 + reg;
        int gr = brow + lrow;
        int key = ((lrow >> 1) & 7) << 3;
        float s = 0.f;
#pragma unroll
        for (int n = 0; n < 4; ++n) {
          int lcol = wcol * 64 + n * 16 + (l & 15);
          float v = acc[m][n][reg] + av[m >> 2][n] + bf2f(Pb[lrow * 256 + (lcol ^ key)]);
          v = v > 0.f ? v : 0.01f * v;          // leaky_relu(0.01)
          s += v * wo[n];
        }
        s += __shfl_xor(s, 1);
        s += __shfl_xor(s, 2);
        s += __shfl_xor(s, 4);
        s += __shfl_xor(s, 8);
        if ((l & 15) == 0)
          atomicAdd(&out[(gr >> 6) * 65 + 1 + (gr & 63)], s);
      }
    }
  } else {
#pragma unroll
    for (int m = 0; m < 8; ++m)
#pragma unroll
      for (int n = 0; n < 4; ++n)
#pragma unroll
        for (int reg = 0; reg < 4; ++reg) {
          int row = brow + wrow * 128 + m * 16 + (l >> 4) * 4 + reg;
          int col = bcol + wcol * 64 + n * 16 + (l & 15);
          C[(size_t)row * ldc + col] = f2bf(acc[m][n][reg]);
        }
  }
}

// ---------------------------------------------------------------------------
extern "C" void kernel_launch(void* const* d_in, const int* in_sizes, int n_in,
                              void* d_out, int out_size, void* d_ws, size_t ws_size,
                              hipStream_t stream) {
  const float* allm  = (const float*)d_in[0];   // [10000,1024]
  const float* ments = (const float*)d_in[1];   // [1024,1024]
  const float* pw    = (const float*)d_in[2];   // [1024,64,64]
  const int*   tidx  = (const int*)d_in[3];     // [1024,64]
  const float* rough = (const float*)d_in[4];   // [1024,64]
  const float* W1    = (const float*)d_in[5];   // [1024,3136]
  const float* b1    = (const float*)d_in[6];   // [1024]
  const float* Wout  = (const float*)d_in[7];   // [1,1024]
  const float* bout  = (const float*)d_in[8];   // [1]
  float* out = (float*)d_out;                   // [1024,65]

  u16* A16    = (u16*)d_ws;                 // 1024*1024 (ments bf16)
  u16* allm16 = A16 + 1024 * 1024;          // 10240*1024 (rows>=10000 zero)
  u16* W1a    = allm16 + 10240 * 1024;      // 1024*1024
  u16* W1b    = W1a + 1024 * 1024;          // 1024*1024
  u16* W1cp   = W1b + 1024 * 1024;          // 1024*1088
  u16* Aproj  = W1cp + 1024 * 1088;         // 1024*1024 bf16 (holds Aproj+b1)
  u16* Bproj  = Aproj + 1024 * 1024;        // 10240*1024 bf16

  size_t need = (size_t)2 * ((size_t)1024*1024 + 10240*1024 + 1024*1024 + 1024*1024
              + 1024*1088 + 1024*1024 + 10240*1024);
  if (ws_size < need) {
    fprintf(stderr, "kernel_launch: ws_size %zu < needed %zu\n", ws_size, need);
    return;
  }

  hipFuncSetAttribute((const void*)&gemm256<false>,
                      hipFuncAttributeMaxDynamicSharedMemorySize, 131072);
  hipFuncSetAttribute((const void*)&gemm256<true>,
                      hipFuncAttributeMaxDynamicSharedMemorySize, 131072);

  // --- conversions / weight splits (bf16) ---
  {
    int t4;
    t4 = 1024 * 256;
    k_cvt<<<(t4 + 255) / 256, 256, 0, stream>>>(W1, 3136, 0,    1024, 256, t4, W1a, 1024, 0);
    k_cvt<<<(t4 + 255) / 256, 256, 0, stream>>>(W1, 3136, 1024, 1024, 256, t4, W1b, 1024, 0);
    k_cvt<<<(t4 + 255) / 256, 256, 0, stream>>>(W1, 3136, 2048, 1024, 256, t4, W1cp, 1088, 0);
    t4 = 1024 * 16;
    k_cvt<<<(t4 + 255) / 256, 256, 0, stream>>>(W1, 3136, 3072, 1024, 16, t4, W1cp, 1088, 1024);
    t4 = 1024 * 256;
    k_cvt<<<(t4 + 255) / 256, 256, 0, stream>>>(ments, 1024, 0, 1024, 256, t4, A16, 1024, 0);
    t4 = 10240 * 256;
    k_cvt<<<(t4 + 255) / 256, 256, 0, stream>>>(allm, 1024, 0, 10000, 256, t4, allm16, 1024, 0);
  }

  // --- projection GEMMs (Aproj gets +b1 folded) ---
  gemm128<<<dim3(8, 8), 256, 0, stream>>>(A16, 1024, W1a, 1024, 16, Aproj, 1024, b1);
  gemm256<false><<<dim3(40, 4), 512, 131072, stream>>>(allm16, 1024, W1b, 1024, 16,
                                                       Bproj, 1024,
                                                       nullptr, nullptr, nullptr,
                                                       nullptr, nullptr, nullptr,
                                                       nullptr, nullptr);

  // --- init out with EPS column and rough+bout ---
  k_init<<<260, 256, 0, stream>>>(rough, bout, out);

  // --- single fused dispatch: builds [a*b|pw] in-kernel, GEMM, epilogue ---
  gemm256<true><<<dim3(256, 4), 512, 131072, stream>>>(nullptr, 0, W1cp, 1088, 17,
                                                       nullptr, 0,
                                                       A16, allm16, pw,
                                                       Aproj, Bproj, Wout,
                                                       tidx, out);
}

// Round 7
// 320.747 us; speedup vs baseline: 2.1830x; 2.1830x over previous
//
#include <hip/hip_runtime.h>
#include <hip/hip_bf16.h>
#include <cstdint>
#include <cstdio>

typedef unsigned short u16;
typedef unsigned int   u32;
typedef __attribute__((ext_vector_type(8))) short bf16x8;   // 8 bf16 (4 VGPRs)
typedef __attribute__((ext_vector_type(4))) float f32x4;
typedef __attribute__((ext_vector_type(4))) u16   u16x4;
typedef __attribute__((ext_vector_type(8))) u16   u16x8;

#define GLOBAL_AS __attribute__((address_space(1)))
#define LDS_AS    __attribute__((address_space(3)))

static __device__ __forceinline__ u16 f2bf(float f) {
  u32 u = __builtin_bit_cast(u32, f);
  u = (u + 0x7fffu + ((u >> 16) & 1u)) >> 16;   // RNE
  return (u16)u;
}
static __device__ __forceinline__ float bf2f(u16 v) {
  return __builtin_bit_cast(float, (u32)v << 16);
}
static __device__ __forceinline__ void gload_lds16(const void* g, void* l) {
  __builtin_amdgcn_global_load_lds((GLOBAL_AS u32*)g, (LDS_AS u32*)l, 16, 0, 0);
}

// ---------------------------------------------------------------------------
__global__ void k_cvt(const float* __restrict__ src, int ld, int c0,
                      int rows_src, int cols4, int total4,
                      u16* __restrict__ dst, int ldd, int dcol) {
  int gid = blockIdx.x * 256 + threadIdx.x;
  if (gid >= total4) return;
  int r = gid / cols4;
  int c = (gid - r * cols4) * 4;
  u16x4 o = {0, 0, 0, 0};
  if (r < rows_src) {
    const float4 v = *(const float4*)&src[(size_t)r * ld + c0 + c];
    o[0] = f2bf(v.x); o[1] = f2bf(v.y); o[2] = f2bf(v.z); o[3] = f2bf(v.w);
  }
  *(u16x4*)&dst[(size_t)r * ldd + dcol + c] = o;
}

// ---------------------------------------------------------------------------
__global__ void k_init(const float* __restrict__ rough,
                       const float* __restrict__ bout,
                       float* __restrict__ out) {
  int i = blockIdx.x * 256 + threadIdx.x;
  if (i >= 1024 * 65) return;
  int bi = i / 65, c = i - bi * 65;
  out[i] = (c == 0) ? 1e-7f : rough[bi * 64 + c - 1] + bout[0];
}

// ---------------------------------------------------------------------------
// gemm128: 128x128 2-phase kernel, used only for the tiny Aproj GEMM.
__global__ __launch_bounds__(256)
void gemm128(const u16* __restrict__ A, int lda,
             const u16* __restrict__ B, int ldb, int Ksteps,
             u16* __restrict__ C, int ldc, const float* __restrict__ bias) {
  __shared__ u16 As[128 * 64];
  __shared__ u16 Bs[128 * 64];
  const int t = threadIdx.x;
  const int w = t >> 6, l = t & 63;
  const int wr = w >> 1, wc = w & 1;
  const int brow = blockIdx.x * 128;
  const int bcol = blockIdx.y * 128;
  const int srow = t >> 3;
  const int scol = (t & 7) * 8;
  const int gsw  = (((t & 7) ^ ((t >> 3) & 7))) * 8;

  f32x4 acc[4][4] = {};
  for (int ks = 0; ks < Ksteps; ++ks) {
    const int kb = ks * 64;
#pragma unroll
    for (int q = 0; q < 4; ++q) {
      int r = q * 32 + srow;
      gload_lds16(A + (size_t)(brow + r) * lda + kb + gsw, &As[r * 64 + scol]);
      gload_lds16(B + (size_t)(bcol + r) * ldb + kb + gsw, &Bs[r * 64 + scol]);
    }
    __syncthreads();
#pragma unroll
    for (int kk = 0; kk < 2; ++kk) {
      bf16x8 af[4], bfr[4];
      const int pg = ((kk * 4 + (l >> 4)) ^ (l & 7)) * 8;
#pragma unroll
      for (int m = 0; m < 4; ++m)
        af[m] = *(const bf16x8*)&As[(wr * 64 + m * 16 + (l & 15)) * 64 + pg];
#pragma unroll
      for (int n = 0; n < 4; ++n)
        bfr[n] = *(const bf16x8*)&Bs[(wc * 64 + n * 16 + (l & 15)) * 64 + pg];
#pragma unroll
      for (int m = 0; m < 4; ++m)
#pragma unroll
        for (int n = 0; n < 4; ++n)
          acc[m][n] = __builtin_amdgcn_mfma_f32_16x16x32_bf16(af[m], bfr[n], acc[m][n], 0, 0, 0);
    }
    __syncthreads();
  }
#pragma unroll
  for (int m = 0; m < 4; ++m)
#pragma unroll
    for (int n = 0; n < 4; ++n)
#pragma unroll
      for (int reg = 0; reg < 4; ++reg) {
        int row = brow + wr * 64 + m * 16 + (l >> 4) * 4 + reg;
        int col = bcol + wc * 64 + n * 16 + (l & 15);
        float v = acc[m][n][reg] + (bias ? bias[col] : 0.f);
        C[(size_t)row * ldc + col] = f2bf(v);
      }
}

// ---------------------------------------------------------------------------
// gemm256: 256x256, BK=64, 512 thr (8 waves 2Mx4N), r5-proven phase shape +
// ledger. FUSED=true builds A in-LDS:
//   - stageRawA: gload_lds raw allm16[mi] rows into As (dest/swizzle = r5).
//   - rmwA(x,h): ds_read own staged 16B, multiply by a16 slice (from LDS),
//     ds_write back. Slots: rmwA(kt,1) after P0-post vmcnt (that wait
//     completes Ah1(kt)); rmwA(kt+1,0) after P3-post vmcnt (completes
//     Ah0(kt+1)). lgkmcnt(0) before the closing barrier publishes writes.
//   - pw tile (NT-1): rmw loads pw f32 directly (garbage pre-stage kept for
//     ledger uniformity; compiler-inserted vmcnt(0) for pw hits a drained
//     queue -> harmless, once per block).
//   - a16 block slice (4 rows x 1024) staged once into LDS in prologue
//     (1 extra VMEM op, accounted in prologue vmcnt(6) ledger).
// Epilogue: Pb swizzled key=((row>>1)&7) src-side + read-side (r5 had 524K
// bank conflicts from linear Pb).
template<bool FUSED>
__global__ __launch_bounds__(512, 1)
void gemm256(const u16* __restrict__ A, int lda,
             const u16* __restrict__ B, int ldb, int NT,
             u16* __restrict__ C, int ldc,
             const u16* __restrict__ a16, const u16* __restrict__ allm16,
             const float* __restrict__ pw,
             const u16* __restrict__ Aproj, const u16* __restrict__ Bproj,
             const float* __restrict__ Wout,
             const int* __restrict__ topidx, float* __restrict__ out) {
  extern __shared__ u16 lds[];
  u16* As = lds;                        // [2buf][2half][128][64], rows bit5-interleaved
  u16* Bs = lds + 2 * 2 * 128 * 64;     // [2buf][256][64]
  u16* a16lds = Bs + 2 * 256 * 64;      // [4][1024] (FUSED only)

  const int t = threadIdx.x;
  const int l = t & 63;
  const int w = t >> 6;                 // 0..7
  const int wrow = w >> 2, wcol = w & 3;
  const int brow = blockIdx.x * 256;
  const int bcol = blockIdx.y * 256;

  const int sr  = t >> 3;               // 0..63
  const int sc  = (t & 7) * 8;          // linear LDS dest col
  const int gsw = ((t & 7) ^ (sr & 7)) * 8;  // pre-swizzled source col

  int mi_[2][2], grow_[2][2];
  if constexpr (FUSED) {
#pragma unroll
    for (int h = 0; h < 2; ++h)
#pragma unroll
      for (int s = 0; s < 2; ++s) {
        int lr = sr + 64 * s;
        int g  = ((lr >> 5) << 6) + h * 32 + (lr & 31);
        grow_[h][s] = brow + g;
        mi_[h][s]   = topidx[brow + g];
      }
  }

  auto stageA = [&](int kt, int h) {    // FUSED=false
    if (kt >= NT) return;
#pragma unroll
    for (int s = 0; s < 2; ++s) {
      int lr = sr + 64 * s;
      int g  = ((lr >> 5) << 6) + h * 32 + (lr & 31);
      gload_lds16(A + (size_t)(brow + g) * lda + kt * 64 + gsw,
                  &As[(((kt & 1) * 2 + h) * 128 + lr) * 64 + sc]);
    }
  };
  auto stageRawA = [&](int kt, int h) { // FUSED=true: raw allm16 gather rows
    if (kt >= NT) return;
#pragma unroll
    for (int s = 0; s < 2; ++s) {
      int lr = sr + 64 * s;
      gload_lds16(allm16 + (size_t)mi_[h][s] * 1024 + kt * 64 + gsw,
                  &As[(((kt & 1) * 2 + h) * 128 + lr) * 64 + sc]);
    }
  };
  auto stageB = [&](int kt, int h) {
    if (kt >= NT) return;
#pragma unroll
    for (int s = 0; s < 2; ++s) {
      int lr = h * 128 + sr + 64 * s;
      gload_lds16(B + (size_t)(bcol + lr) * ldb + kt * 64 + gsw,
                  &Bs[((kt & 1) * 256 + lr) * 64 + sc]);
    }
  };
  // in-LDS raw->product conversion; caller guarantees data landed + no readers
  auto rmwA = [&](int kt1, int h) {
    if (kt1 >= NT) return;
    const int cb = kt1 & 1;
    if (kt1 == NT - 1) {                // pw tile: overwrite with bf16(pw)
#pragma unroll
      for (int s = 0; s < 2; ++s) {
        int lr = sr + 64 * s;
        const float* p = &pw[(size_t)grow_[h][s] * 64 + gsw];
        float4 p0 = *(const float4*)p;
        float4 p1 = *(const float4*)(p + 4);
        u16x8 o;
        o[0] = f2bf(p0.x); o[1] = f2bf(p0.y); o[2] = f2bf(p0.z); o[3] = f2bf(p0.w);
        o[4] = f2bf(p1.x); o[5] = f2bf(p1.y); o[6] = f2bf(p1.z); o[7] = f2bf(p1.w);
        *(u16x8*)&As[((cb * 2 + h) * 128 + lr) * 64 + sc] = o;
      }
    } else {
#pragma unroll
      for (int s = 0; s < 2; ++s) {
        int lr = sr + 64 * s;
        u16x8 b = *(const u16x8*)&As[((cb * 2 + h) * 128 + lr) * 64 + sc];
        u16x8 a = *(const u16x8*)&a16lds[(lr >> 5) * 1024 + kt1 * 64 + gsw];
        u16x8 o;
#pragma unroll
        for (int j = 0; j < 8; ++j) o[j] = f2bf(bf2f(a[j]) * bf2f(b[j]));
        *(u16x8*)&As[((cb * 2 + h) * 128 + lr) * 64 + sc] = o;
      }
    }
  };

  f32x4 acc[8][4] = {};

  // ---- prologue ----
  if constexpr (FUSED) {
    // a16 block slice -> LDS (1 VMEM op, first in queue)
    gload_lds16(&a16[(size_t)((brow >> 6) + (t >> 7)) * 1024 + (t & 127) * 8],
                &a16lds[(size_t)t * 8]);
    stageB(0, 0); stageB(0, 1); stageRawA(0, 0); stageRawA(0, 1);
    stageB(1, 0); stageB(1, 1);
    // queue: a16(1),B0(4),A0h0(2),A0h1(2),B1(4)=13; vmcnt(6) completes
    // a16+B0+A0h0, leaves [A0h1,B1h0,B1h1]=6 (steady-state entry).
    asm volatile("s_waitcnt vmcnt(6)" ::: "memory");
    rmwA(0, 0);
    asm volatile("s_waitcnt lgkmcnt(0)" ::: "memory");
  } else {
    stageB(0, 0); stageB(0, 1); stageA(0, 0); stageA(0, 1);
    stageB(1, 0); stageB(1, 1);
    asm volatile("s_waitcnt vmcnt(6)" ::: "memory");
  }
  __builtin_amdgcn_s_barrier();

  for (int kt = 0; kt < NT; ++kt) {
    const int cbuf = kt & 1;
    bf16x8 bfr[4][2];
#pragma unroll
    for (int q = 0; q < 4; ++q) {
      // --- ds reads (pre-barrier) ---
      if (q == 0) {
#pragma unroll
        for (int n = 0; n < 4; ++n) {
          int row = wcol * 64 + n * 16 + (l & 15);
#pragma unroll
          for (int kk = 0; kk < 2; ++kk) {
            int gran = (kk * 4 + (l >> 4)) ^ (l & 7);
            bfr[n][kk] = *(const bf16x8*)&Bs[(cbuf * 256 + row) * 64 + gran * 8];
          }
        }
      }
      bf16x8 af[2][2];
#pragma unroll
      for (int m2 = 0; m2 < 2; ++m2) {
        int m = 2 * q + m2;
        int g = wrow * 128 + m * 16 + (l & 15);
        int lra = ((g >> 6) << 5) + (g & 31);
#pragma unroll
        for (int kk = 0; kk < 2; ++kk) {
          int gran = (kk * 4 + (l >> 4)) ^ (l & 7);
          af[m2][kk] = *(const bf16x8*)&As[((cbuf * 2 + (q & 1)) * 128 + lra) * 64 + gran * 8];
        }
      }

      // --- stage exactly one half-tile ---
      if constexpr (FUSED) {
        if      (q == 0) stageRawA(kt + 1, 0);
        else if (q == 1) stageRawA(kt + 1, 1);
        else if (q == 2) stageB(kt + 2, 0);
        else             stageB(kt + 2, 1);
      } else {
        if      (q == 0) stageA(kt + 1, 0);
        else if (q == 1) stageA(kt + 1, 1);
        else if (q == 2) stageB(kt + 2, 0);
        else             stageB(kt + 2, 1);
      }

      if (q == 0) asm volatile("s_waitcnt lgkmcnt(8)" ::: "memory");
      __builtin_amdgcn_s_barrier();
      asm volatile("s_waitcnt lgkmcnt(0)" ::: "memory");
      __builtin_amdgcn_sched_barrier(0);
      __builtin_amdgcn_s_setprio(1);
#pragma unroll
      for (int m2 = 0; m2 < 2; ++m2)
#pragma unroll
        for (int n = 0; n < 4; ++n)
#pragma unroll
          for (int kk = 0; kk < 2; ++kk)
            acc[2 * q + m2][n] = __builtin_amdgcn_mfma_f32_16x16x32_bf16(
                af[m2][kk], bfr[n][kk], acc[2 * q + m2][n], 0, 0, 0);
      __builtin_amdgcn_s_setprio(0);

      // --- counted waits + RMW slots, then closing barrier ---
      if (q == 0) {
        if (kt + 1 < NT) asm volatile("s_waitcnt vmcnt(6)" ::: "memory");
        else             asm volatile("s_waitcnt vmcnt(0)" ::: "memory");
        if constexpr (FUSED) {
          rmwA(kt, 1);                  // Ah1(kt) landed by the wait above
          asm volatile("s_waitcnt lgkmcnt(0)" ::: "memory");
        }
      } else if (q == 3 && kt + 1 < NT) {
        if (kt + 2 < NT) asm volatile("s_waitcnt vmcnt(6)" ::: "memory");
        else             asm volatile("s_waitcnt vmcnt(2)" ::: "memory");
        if constexpr (FUSED) {
          rmwA(kt + 1, 0);              // Ah0(kt+1) landed by the wait above
          asm volatile("s_waitcnt lgkmcnt(0)" ::: "memory");
        }
      }
      __builtin_amdgcn_s_barrier();
    }
  }

  // --- epilogue ---
  if constexpr (FUSED) {
    __syncthreads();
    u16* Pb = lds;                      // [256][256], src+read XOR key=((row>>1)&7)
#pragma unroll
    for (int pass = 0; pass < 16; ++pass) {
      int rr = pass * 16 + (t >> 5);
      int mi = topidx[brow + rr];
      int cc = (t & 31) * 8;
      int scc = cc ^ (((rr >> 1) & 7) << 3);
      gload_lds16(&Bproj[(size_t)mi * 1024 + bcol + scc], &Pb[rr * 256 + cc]);
    }
    asm volatile("s_waitcnt vmcnt(0)" ::: "memory");
    __syncthreads();

    float wo[4], av[2][4];
    const int bi0 = (brow >> 6) + wrow * 2;
#pragma unroll
    for (int n = 0; n < 4; ++n) {
      int col = bcol + wcol * 64 + n * 16 + (l & 15);
      wo[n] = Wout[col];
#pragma unroll
      for (int j = 0; j < 2; ++j)
        av[j][n] = bf2f(Aproj[(size_t)(bi0 + j) * 1024 + col]);   // b1 pre-folded
    }
#pragma unroll
    for (int m = 0; m < 8; ++m) {
#pragma unroll
      for (int reg = 0; reg < 4; ++reg) {
        int lrow = wrow * 128 + m * 16 + (l >> 4) * 4 + reg;
        int gr = brow + lrow;
        int key = ((lrow >> 1) & 7) << 3;
        float s = 0.f;
#pragma unroll
        for (int n = 0; n < 4; ++n) {
          int lcol = wcol * 64 + n * 16 + (l & 15);
          float v = acc[m][n][reg] + av[m >> 2][n] + bf2f(Pb[lrow * 256 + (lcol ^ key)]);
          v = v > 0.f ? v : 0.01f * v;          // leaky_relu(0.01)
          s += v * wo[n];
        }
        s += __shfl_xor(s, 1);
        s += __shfl_xor(s, 2);
        s += __shfl_xor(s, 4);
        s += __shfl_xor(s, 8);
        if ((l & 15) == 0)
          atomicAdd(&out[(gr >> 6) * 65 + 1 + (gr & 63)], s);
      }
    }
  } else {
#pragma unroll
    for (int m = 0; m < 8; ++m)
#pragma unroll
      for (int n = 0; n < 4; ++n)
#pragma unroll
        for (int reg = 0; reg < 4; ++reg) {
          int row = brow + wrow * 128 + m * 16 + (l >> 4) * 4 + reg;
          int col = bcol + wcol * 64 + n * 16 + (l & 15);
          C[(size_t)row * ldc + col] = f2bf(acc[m][n][reg]);
        }
  }
}

// ---------------------------------------------------------------------------
extern "C" void kernel_launch(void* const* d_in, const int* in_sizes, int n_in,
                              void* d_out, int out_size, void* d_ws, size_t ws_size,
                              hipStream_t stream) {
  const float* allm  = (const float*)d_in[0];   // [10000,1024]
  const float* ments = (const float*)d_in[1];   // [1024,1024]
  const float* pw    = (const float*)d_in[2];   // [1024,64,64]
  const int*   tidx  = (const int*)d_in[3];     // [1024,64]
  const float* rough = (const float*)d_in[4];   // [1024,64]
  const float* W1    = (const float*)d_in[5];   // [1024,3136]
  const float* b1    = (const float*)d_in[6];   // [1024]
  const float* Wout  = (const float*)d_in[7];   // [1,1024]
  const float* bout  = (const float*)d_in[8];   // [1]
  float* out = (float*)d_out;                   // [1024,65]

  u16* A16    = (u16*)d_ws;                 // 1024*1024 (ments bf16)
  u16* allm16 = A16 + 1024 * 1024;          // 10240*1024 (rows>=10000 zero)
  u16* W1a    = allm16 + 10240 * 1024;      // 1024*1024
  u16* W1b    = W1a + 1024 * 1024;          // 1024*1024
  u16* W1cp   = W1b + 1024 * 1024;          // 1024*1088
  u16* Aproj  = W1cp + 1024 * 1088;         // 1024*1024 bf16 (holds Aproj+b1)
  u16* Bproj  = Aproj + 1024 * 1024;        // 10240*1024 bf16

  size_t need = (size_t)2 * ((size_t)1024*1024 + 10240*1024 + 1024*1024 + 1024*1024
              + 1024*1088 + 1024*1024 + 10240*1024);
  if (ws_size < need) {
    fprintf(stderr, "kernel_launch: ws_size %zu < needed %zu\n", ws_size, need);
    return;
  }

  hipFuncSetAttribute((const void*)&gemm256<false>,
                      hipFuncAttributeMaxDynamicSharedMemorySize, 131072);
  hipFuncSetAttribute((const void*)&gemm256<true>,
                      hipFuncAttributeMaxDynamicSharedMemorySize, 139264);

  // --- conversions / weight splits (bf16) ---
  {
    int t4;
    t4 = 1024 * 256;
    k_cvt<<<(t4 + 255) / 256, 256, 0, stream>>>(W1, 3136, 0,    1024, 256, t4, W1a, 1024, 0);
    k_cvt<<<(t4 + 255) / 256, 256, 0, stream>>>(W1, 3136, 1024, 1024, 256, t4, W1b, 1024, 0);
    k_cvt<<<(t4 + 255) / 256, 256, 0, stream>>>(W1, 3136, 2048, 1024, 256, t4, W1cp, 1088, 0);
    t4 = 1024 * 16;
    k_cvt<<<(t4 + 255) / 256, 256, 0, stream>>>(W1, 3136, 3072, 1024, 16, t4, W1cp, 1088, 1024);
    t4 = 1024 * 256;
    k_cvt<<<(t4 + 255) / 256, 256, 0, stream>>>(ments, 1024, 0, 1024, 256, t4, A16, 1024, 0);
    t4 = 10240 * 256;
    k_cvt<<<(t4 + 255) / 256, 256, 0, stream>>>(allm, 1024, 0, 10000, 256, t4, allm16, 1024, 0);
  }

  // --- projection GEMMs (Aproj gets +b1 folded) ---
  gemm128<<<dim3(8, 8), 256, 0, stream>>>(A16, 1024, W1a, 1024, 16, Aproj, 1024, b1);
  gemm256<false><<<dim3(40, 4), 512, 131072, stream>>>(allm16, 1024, W1b, 1024, 16,
                                                       Bproj, 1024,
                                                       nullptr, nullptr, nullptr,
                                                       nullptr, nullptr, nullptr,
                                                       nullptr, nullptr);

  // --- init out with EPS column and rough+bout ---
  k_init<<<260, 256, 0, stream>>>(rough, bout, out);

  // --- single fused dispatch: raw-gather staging + in-LDS multiply + GEMM ---
  gemm256<true><<<dim3(256, 4), 512, 139264, stream>>>(nullptr, 0, W1cp, 1088, 17,
                                                       nullptr, 0,
                                                       A16, allm16, pw,
                                                       Aproj, Bproj, Wout,
                                                       tidx, out);
}